// Round 18
// baseline (36.329 us; speedup 1.0000x reference)
//
#include <hip/hip_runtime.h>
#include <math.h>

#define BB 4096
#define DD 1024
#define KK 5
#define PP 1323

// (2*pi)^(-3/2)
#define INV_2PI_POW15 0.06349363593424097f

// ---- fused config ----
#define GR   16        // b-rows/cols per block -> 256 blocks (1/CU)
#define NWV  8         // waves per block (512 threads)
#define HT   512       // block threads
#define RST  13        // s_red inner stride (12 + 1)
#define CSTR 49        // s_c inner stride
#define NPASS 42       // ceil(1323 / 32)
#define NGRP  7        // 42 = 7 groups x 6 passes

typedef short  bf16x8 __attribute__((ext_vector_type(8)));
typedef float  f32x4  __attribute__((ext_vector_type(4)));

__device__ __forceinline__ short f2bf(float f) {
    union { float f; unsigned u; } x; x.f = f;
    const unsigned r = x.u + 0x7fffu + ((x.u >> 16) & 1u);  // RNE
    return (short)(r >> 16);
}
__device__ __forceinline__ float softplus_f(float x) {
    return (x > 20.f) ? x : log1pf(expf(x));
}

// ---------------------------------------------------------------------------
// Single fused kernel. 256 blocks x 512 thr. Block g owns batch rows
// [16g, 16g+16):
//   Phase A (head): 8-wave split-K MFMA GEMV (B gathered direct from raw W,
//     L2-resident; A direct from rep), 8-deep LDS reduce, 80-thread tail ->
//     s_par (LDS) + s_L, coalesced Lout write.
//   Phase B (eval): same block evaluates out[p][b] for its 16 columns,
//     all 1323 p. Per p-row the block reads 192 contiguous bytes (3 full
//     cache lines); params from LDS. No cross-block dependency anywhere.
// ---------------------------------------------------------------------------
__global__ __launch_bounds__(HT, 2) void fused_kernel(
    const float* __restrict__ rep,
    const float* __restrict__ dxyz,
    const float* __restrict__ Wmix,
    const float* __restrict__ bmix,
    const float* __restrict__ Wmean,
    const float* __restrict__ bmean,
    const float* __restrict__ Wscale,
    const float* __restrict__ bscale,
    float* __restrict__ out,
    float* __restrict__ Lout)
{
    __shared__ float s_red[NWV][64][RST];   // 26.6 KB
    __shared__ float s_c[GR][CSTR];         // 3.1 KB
    __shared__ float s_L[GR][KK][6];        // 1.9 KB
    __shared__ float s_par[GR][50];         // 3.2 KB (stride 50: conflict-free)

    const int t  = threadIdx.x;
    const int w  = t >> 6;          // wave 0..7
    const int l  = t & 63;
    const int lm = l & 15;
    const int lk = (l >> 4) * 8;
    const int b0 = blockIdx.x * GR;

    // ======================= Phase A: head =================================
    // B-fragments direct from raw W (predicated strided gather, L2-resident)
    bf16x8 bh[4][3];
#pragma unroll
    for (int nt = 0; nt < 3; ++nt) {
        const int j0 = nt * 16 + lm;
        const float* bp; int ncol, col;
        if (j0 < 5)       { bp = Wmix;   ncol = 5;  col = j0; }
        else if (j0 < 17) { bp = Wmean;  ncol = 12; col = j0 - 5; }
        else if (j0 < 47) { bp = Wscale; ncol = 30; col = j0 - 17; }
        else              { bp = Wmix;   ncol = 0;  col = 0; }   // j0==47 pad
        const bool valid = (j0 < 47);
#pragma unroll
        for (int kt = 0; kt < 4; ++kt) {
            const int k0 = (w * 4 + kt) * 32 + lk;
            float f[8];
#pragma unroll
            for (int e = 0; e < 8; ++e)
                f[e] = valid ? bp[(size_t)(k0 + e) * ncol + col] : 0.f;
#pragma unroll
            for (int e = 0; e < 8; ++e)
                bh[kt][nt][e] = f2bf(f[e]);
        }
    }

    // A (rep) loads upfront
    f32x4 a0[4], a1[4];
#pragma unroll
    for (int kt = 0; kt < 4; ++kt) {
        const int kof = (w * 4 + kt) * 32 + lk;
        const float* arow = rep + (size_t)(b0 + lm) * DD + kof;
        a0[kt] = *(const f32x4*)(arow);
        a1[kt] = *(const f32x4*)(arow + 4);
    }

    // convert + MFMA
    f32x4 acc[3] = {f32x4{0,0,0,0}, f32x4{0,0,0,0}, f32x4{0,0,0,0}};
#pragma unroll
    for (int kt = 0; kt < 4; ++kt) {
        bf16x8 ah;
#pragma unroll
        for (int u = 0; u < 4; ++u) {
            ah[u]     = f2bf(a0[kt][u]);
            ah[u + 4] = f2bf(a1[kt][u]);
        }
#pragma unroll
        for (int nt = 0; nt < 3; ++nt)
            acc[nt] = __builtin_amdgcn_mfma_f32_16x16x32_bf16(ah, bh[kt][nt], acc[nt], 0, 0, 0);
    }

    // 8-deep cross-wave reduce via LDS
#pragma unroll
    for (int nt = 0; nt < 3; ++nt)
#pragma unroll
        for (int r = 0; r < 4; ++r)
            s_red[w][l][nt * 4 + r] = acc[nt][r];
    __syncthreads();

    // cooperative sum into s_c[b_loc][j]; C layout [m89]:
    // col(=j) = lane&15, row(=b_loc) = (lane>>4)*4 + reg
    for (int e = t; e < GR * 47; e += HT) {
        const int b_loc = e & 15;
        const int j     = e >> 4;
        const int lane  = ((b_loc >> 2) << 4) | (j & 15);
        const int reg   = ((j >> 4) << 2) | (b_loc & 3);
        float s = 0.f;
#pragma unroll
        for (int q = 0; q < NWV; ++q) s += s_red[q][lane][reg];
        s_c[b_loc][j] = s;
    }
    __syncthreads();

    // tail: 80 threads = 16 b x 5 k -> s_L + s_par
    if (t < GR * KK) {
        const int k     = t >> 4;
        const int b_loc = t & 15;

        float logits[KK];
#pragma unroll
        for (int kk = 0; kk < KK; ++kk) logits[kk] = s_c[b_loc][kk] + bmix[kk];

        float m[3];
#pragma unroll
        for (int c = 0; c < 3; ++c)
            m[c] = (k > 0) ? (s_c[b_loc][5 + (k - 1) * 3 + c] + bmean[(k - 1) * 3 + c]) : 0.f;

        float sc[6];
#pragma unroll
        for (int c = 0; c < 6; ++c)
            sc[c] = s_c[b_loc][17 + k * 6 + c] + bscale[k * 6 + c];

        float mx = logits[0];
#pragma unroll
        for (int kk = 1; kk < KK; ++kk) mx = fmaxf(mx, logits[kk]);
        float den = 0.f;
#pragma unroll
        for (int kk = 0; kk < KK; ++kk) den += expf(logits[kk] - mx);
        const float wgt = expf(logits[k] - mx) / den;

        const float L00 = softplus_f(sc[0]);
        const float L10 = sc[1];
        const float L11 = softplus_f(sc[2]);
        const float L20 = sc[3];
        const float L21 = sc[4];
        const float L22 = softplus_f(sc[5]);

        const float r00 = 1.f / L00;
        const float r11 = 1.f / L11;
        const float r22 = 1.f / L22;
        const float a   = wgt * r00 * r11 * r22 * INV_2PI_POW15;

        s_L[b_loc][k][0] = L00;
        s_L[b_loc][k][1] = L10;
        s_L[b_loc][k][2] = L11;
        s_L[b_loc][k][3] = L20;
        s_L[b_loc][k][4] = L21;
        s_L[b_loc][k][5] = L22;

        float pv[10] = { m[0], m[1], m[2], r00, L10, r11, L20, L21, r22, a };
#pragma unroll
        for (int i = 0; i < 10; ++i)
            s_par[b_loc][k * 10 + i] = pv[i];
    }
    __syncthreads();

    // coalesced Lout write: 720 contiguous floats
    for (int e = t; e < GR * KK * 9; e += HT) {
        const int b_loc = e / 45;
        const int rem   = e - b_loc * 45;
        const int k     = rem / 9;
        const int e9    = rem - k * 9;
        const int rr    = e9 / 3;
        const int cc    = e9 - rr * 3;
        const float v = (cc > rr) ? 0.f : s_L[b_loc][k][(rr * (rr + 1)) / 2 + cc];
        Lout[(size_t)b0 * 45 + e] = v;
    }

    // ======================= Phase B: eval =================================
    const int b_loc = t & 15;
    const int prow  = t >> 4;       // 0..31
    const int bg    = b0 + b_loc;

    float pr[50];
#pragma unroll
    for (int i = 0; i < 50; ++i) pr[i] = s_par[b_loc][i];

#pragma unroll 1
    for (int grp = 0; grp < NGRP; ++grp) {
        float x[6][3];
#pragma unroll
        for (int u = 0; u < 6; ++u) {
            const int p = grp * 192 + u * 32 + prow;
            if (p < PP) {
                const float* xv = dxyz + ((size_t)p * BB + bg) * 3;
                x[u][0] = xv[0];
                x[u][1] = xv[1];
                x[u][2] = xv[2];
            }
        }
#pragma unroll
        for (int u = 0; u < 6; ++u) {
            const int p = grp * 192 + u * 32 + prow;
            if (p < PP) {
                float res = 0.f;
#pragma unroll
                for (int k = 0; k < KK; ++k) {
                    const float d0 = x[u][0] - pr[k * 10 + 0];
                    const float d1 = x[u][1] - pr[k * 10 + 1];
                    const float d2 = x[u][2] - pr[k * 10 + 2];
                    const float z0 = d0 * pr[k * 10 + 3];
                    const float z1 = fmaf(-pr[k * 10 + 4], z0, d1) * pr[k * 10 + 5];
                    const float z2 = fmaf(-pr[k * 10 + 7], z1, fmaf(-pr[k * 10 + 6], z0, d2)) * pr[k * 10 + 8];
                    const float q  = fmaf(z2, z2, fmaf(z1, z1, z0 * z0));
                    res = fmaf(pr[k * 10 + 9], __expf(-0.5f * q), res);
                }
                out[(size_t)p * BB + bg] = res;
            }
        }
    }
}

extern "C" void kernel_launch(void* const* d_in, const int* in_sizes, int n_in,
                              void* d_out, int out_size, void* d_ws, size_t ws_size,
                              hipStream_t stream) {
    const float* rep    = (const float*)d_in[0];
    const float* dxyz   = (const float*)d_in[1];
    const float* Wmix   = (const float*)d_in[2];
    const float* bmix   = (const float*)d_in[3];
    const float* Wmean  = (const float*)d_in[4];
    const float* bmean  = (const float*)d_in[5];
    const float* Wscale = (const float*)d_in[6];
    const float* bscale = (const float*)d_in[7];

    float* out  = (float*)d_out;
    float* Lout = out + (size_t)BB * PP;          // second tuple output

    fused_kernel<<<BB / GR, HT, 0, stream>>>(rep, dxyz, Wmix, bmix, Wmean, bmean,
                                             Wscale, bscale, out, Lout);
}